// Round 3
// baseline (1165.399 us; speedup 1.0000x reference)
//
#include <hip/hip_runtime.h>
#include <hip/hip_bf16.h>
#include <stdint.h>

typedef unsigned short u16;
typedef u16 ushort8 __attribute__((ext_vector_type(8)));
typedef __bf16 bf16x8 __attribute__((ext_vector_type(8)));
typedef float f32x4 __attribute__((ext_vector_type(4)));

enum {
  EPI_F32S = 0,      // f32 out into split-K slice ks
  EPI_BF16 = 1,      // plain bf16 out
  EPI_SILU = 2,      // silu(v) -> bf16
  EPI_SILU_PRE = 3,  // X2 = v (preact), C = silu(v)
  EPI_DIFF = 4,      // C = v - X1
  EPI_DSILU = 5,     // C = v * silu'(X1)   (X1 may alias C)
  EPI_F32 = 6        // plain f32 out
};

__device__ __forceinline__ float bf2f(u16 u) {
  union { uint32_t i; float f; } c; c.i = ((uint32_t)u) << 16; return c.f;
}
__device__ __forceinline__ u16 f2bf(float f) {
  union { float f; uint32_t i; } c; c.f = f;
  uint32_t x = c.i;
  return (u16)((x + 0x7fffu + ((x >> 16) & 1u)) >> 16);  // RNE
}
__device__ __forceinline__ float sigm(float x) { return 1.0f / (1.0f + __expf(-x)); }

// f32 -> bf16 conversion, 8 elems/thread; n multiple of 8
__global__ __launch_bounds__(256)
void cvt_kernel(const float* __restrict__ in, u16* __restrict__ out, long n) {
  const long i = ((long)blockIdx.x * 256 + threadIdx.x) * 8;
  if (i >= n) return;
  f32x4 a = *(const f32x4*)(in + i);
  f32x4 b = *(const f32x4*)(in + i + 4);
  ushort8 v;
#pragma unroll
  for (int e = 0; e < 4; ++e) v[e] = f2bf(a[e]);
#pragma unroll
  for (int e = 0; e < 4; ++e) v[4 + e] = f2bf(b[e]);
  *(ushort8*)(out + i) = v;
}

// ---------------------------------------------------------------------------
// NT GEMM: C[M,N] = epi( sum_k A[m,k]*B[n,k] ), A:(M,K) B:(N,K) row-major bf16.
// 128x128 tile, BK=32, 256 threads (4 waves, 2x2), 16x16x32 bf16 MFMA.
// Register-staged LDS (global->reg->ds_write_b128), single-buffered.
// Split-K: grid = (M/128)*(N/128)*SK, slice ks covers k in [ks*K/SK, ...).
// ---------------------------------------------------------------------------
template<int EPI>
__global__ __launch_bounds__(256)
void gemm_nt(const u16* __restrict__ A, const u16* __restrict__ B,
             void* Cp, const u16* X1, u16* X2,
             int M, int N, int K, int SK) {
  __shared__ u16 lA[4096];  // [128][32]
  __shared__ u16 lB[4096];
  const int t = threadIdx.x;
  const int w = t >> 6, l = t & 63;
  const int nb = N >> 7;
  const int tilesPer = (M >> 7) * nb;
  int bid = blockIdx.x;
  const int ks = bid / tilesPer;
  bid -= ks * tilesPer;
  const int bm = bid / nb;
  const int bn = bid - bm * nb;
  const long mBase = (long)bm << 7;
  const long nBase = (long)bn << 7;
  const int wr = w >> 1, wc = w & 1;
  const int kLen = K / SK;

  f32x4 acc[4][4];
#pragma unroll
  for (int i = 0; i < 4; ++i)
#pragma unroll
    for (int j = 0; j < 4; ++j) acc[i][j] = f32x4{0.f, 0.f, 0.f, 0.f};

  // staging: thread t owns row (t>>1), 16-u16 half (t&1) of the 32-wide K slab
  const int sr = t >> 1;          // 0..127
  const int sc = (t & 1) << 4;    // 0 or 16
  const u16* gA = A + (mBase + sr) * (long)K + sc + (long)ks * kLen;
  const u16* gB = B + (nBase + sr) * (long)K + sc + (long)ks * kLen;
  u16* wApt = &lA[sr * 32 + sc];
  u16* wBpt = &lB[sr * 32 + sc];

  const int lr = l & 15;
  const int lk = (l >> 4) << 3;
  const int lg = l >> 4;

  for (int k0 = 0; k0 < kLen; k0 += 32) {
    ushort8 a0 = *(const ushort8*)(gA + k0);
    ushort8 a1 = *(const ushort8*)(gA + k0 + 8);
    ushort8 b0 = *(const ushort8*)(gB + k0);
    ushort8 b1 = *(const ushort8*)(gB + k0 + 8);
    __syncthreads();  // previous iteration's ds_reads drained before overwrite
    *(ushort8*)wApt = a0;
    *(ushort8*)(wApt + 8) = a1;
    *(ushort8*)wBpt = b0;
    *(ushort8*)(wBpt + 8) = b1;
    __syncthreads();
    bf16x8 av[4], bv[4];
#pragma unroll
    for (int m = 0; m < 4; ++m) {
      ushort8 u = *(const ushort8*)&lA[((wr << 6) + (m << 4) + lr) * 32 + lk];
      av[m] = __builtin_bit_cast(bf16x8, u);
    }
#pragma unroll
    for (int n = 0; n < 4; ++n) {
      ushort8 u = *(const ushort8*)&lB[((wc << 6) + (n << 4) + lr) * 32 + lk];
      bv[n] = __builtin_bit_cast(bf16x8, u);
    }
#pragma unroll
    for (int m = 0; m < 4; ++m)
#pragma unroll
      for (int n = 0; n < 4; ++n)
        acc[m][n] = __builtin_amdgcn_mfma_f32_16x16x32_bf16(av[m], bv[n], acc[m][n], 0, 0, 0);
  }

  // epilogue: C/D frag layout col = lane&15, row = (lane>>4)*4 + r  (m89-verified)
#pragma unroll
  for (int m = 0; m < 4; ++m) {
#pragma unroll
    for (int n = 0; n < 4; ++n) {
#pragma unroll
      for (int r = 0; r < 4; ++r) {
        const long row = mBase + (wr << 6) + (m << 4) + (lg << 2) + r;
        const long col = nBase + (wc << 6) + (n << 4) + lr;
        const long idx = row * N + col;
        const float v = acc[m][n][r];
        if constexpr (EPI == EPI_F32S) {
          ((float*)Cp)[(long)ks * M * N + idx] = v;
        } else if constexpr (EPI == EPI_F32) {
          ((float*)Cp)[idx] = v;
        } else if constexpr (EPI == EPI_BF16) {
          ((u16*)Cp)[idx] = f2bf(v);
        } else if constexpr (EPI == EPI_SILU) {
          ((u16*)Cp)[idx] = f2bf(v * sigm(v));
        } else if constexpr (EPI == EPI_SILU_PRE) {
          X2[idx] = f2bf(v);
          ((u16*)Cp)[idx] = f2bf(v * sigm(v));
        } else if constexpr (EPI == EPI_DIFF) {
          ((u16*)Cp)[idx] = f2bf(v - bf2f(X1[idx]));
        } else if constexpr (EPI == EPI_DSILU) {
          const float h = bf2f(X1[idx]);
          const float s = sigm(h);
          ((u16*)Cp)[idx] = f2bf(v * (s + h * s * (1.0f - s)));
        }
      }
    }
  }
}

// row-wise L2 normalize, D=1024, bf16 in-place, one wave per row
__global__ __launch_bounds__(256)
void l2norm_kernel(u16* a) {
  const int w = threadIdx.x >> 6, l = threadIdx.x & 63;
  const long row = (long)blockIdx.x * 4 + w;
  u16* p = a + row * 1024 + l * 16;
  ushort8 v0 = *(const ushort8*)p;
  ushort8 v1 = *(const ushort8*)(p + 8);
  float ss = 0.0f;
#pragma unroll
  for (int e = 0; e < 8; ++e) { float f = bf2f(v0[e]); ss += f * f; }
#pragma unroll
  for (int e = 0; e < 8; ++e) { float f = bf2f(v1[e]); ss += f * f; }
#pragma unroll
  for (int off = 32; off >= 1; off >>= 1) ss += __shfl_xor(ss, off, 64);
  const float sc = 1.0f / fmaxf(sqrtf(ss), 1e-12f);
#pragma unroll
  for (int e = 0; e < 8; ++e) v0[e] = f2bf(bf2f(v0[e]) * sc);
#pragma unroll
  for (int e = 0; e < 8; ++e) v1[e] = f2bf(bf2f(v1[e]) * sc);
  *(ushort8*)p = v0;
  *(ushort8*)(p + 8) = v1;
}

// 64x64 LDS tile transpose, bf16, R,C multiples of 64. grid (C/64, R/64)
__global__ __launch_bounds__(256)
void transpose_kernel(const u16* __restrict__ in, u16* __restrict__ out, int R, int C) {
  __shared__ u16 tile[64 * 72];
  const int t = threadIdx.x;
  const long br = blockIdx.y, bc = blockIdx.x;
#pragma unroll
  for (int i = 0; i < 2; ++i) {
    const int e = i * 256 + t;
    const int r = e >> 3, c0 = (e & 7) << 3;
    ushort8 v = *(const ushort8*)&in[(br * 64 + r) * C + bc * 64 + c0];
    *(ushort8*)&tile[r * 72 + c0] = v;
  }
  __syncthreads();
#pragma unroll
  for (int i = 0; i < 2; ++i) {
    const int e = i * 256 + t;
    const int r = e >> 3, c0 = (e & 7) << 3;
    ushort8 v;
#pragma unroll
    for (int j = 0; j < 8; ++j) v[j] = tile[(c0 + j) * 72 + r];
    *(ushort8*)&out[(bc * 64 + r) * R + br * 64 + c0] = v;
  }
}

// x:(4,2048,1024) f32 -> xsum:(4,1024) f32 partial sums over S. grid (16,16)
__global__ __launch_bounds__(256)
void xmean_kernel(const float* __restrict__ x, float* __restrict__ xsum) {
  const int i = blockIdx.x * 256 + threadIdx.x;  // b*1024 + d
  const int b = i >> 10, d = i & 1023;
  const int s0 = blockIdx.y << 7;
  const float* p = x + ((long)b * 2048 + s0) * 1024 + d;
  float s = 0.0f;
  for (int k = 0; k < 128; ++k) s += p[(long)k * 1024];
  atomicAdd(&xsum[i], s);
}

// gacc[g] += sigmoid(dot(xsum[b]/2048, W_g[j]) + bias_g[j]); one wave per dot
__global__ __launch_bounds__(256)
void gates_kernel(const float* __restrict__ xsum,
                  const float* __restrict__ W0, const float* __restrict__ b0,
                  const float* __restrict__ W1, const float* __restrict__ b1,
                  const float* __restrict__ W2, const float* __restrict__ b2,
                  float* __restrict__ gacc) {
  const int gw = blockIdx.x * 4 + (threadIdx.x >> 6);
  const int l = threadIdx.x & 63;
  const int g = gw >> 12;
  const int rem = gw & 4095;
  const int b = rem >> 10, j = rem & 1023;
  const float* W = (g == 0) ? W0 : ((g == 1) ? W1 : W2);
  const float* bias = (g == 0) ? b0 : ((g == 1) ? b1 : b2);
  const float* xr = xsum + (b << 10) + (l << 4);
  const float* wrow = W + ((long)j << 10) + (l << 4);
  float s = 0.0f;
#pragma unroll
  for (int e = 0; e < 16; ++e) s += wrow[e] * xr[e];
#pragma unroll
  for (int off = 32; off >= 1; off >>= 1) s += __shfl_xor(s, off, 64);
  if (l == 0) {
    const float z = s * (1.0f / 2048.0f) + bias[j];
    atomicAdd(&gacc[g], sigm(z));
  }
}

// new_m = eta*mom - theta*gscale*g ; new_w = (1-alpha)*w + new_m ; g summed over 4 split-K slices
__global__ __launch_bounds__(256)
void update_kernel(const float* __restrict__ graw, const float* __restrict__ w,
                   const float* __restrict__ mom, float* __restrict__ outw,
                   float* __restrict__ outm, const float* __restrict__ gacc,
                   float gscale, int n) {
  const int i = blockIdx.x * 256 + threadIdx.x;
  if (i >= n) return;
  const float alpha = gacc[0] * (1.0f / 4096.0f);
  const float theta = gacc[1] * (1.0f / 4096.0f);
  const float eta   = gacc[2] * (1.0f / 4096.0f);
  const float g4 = graw[i] + graw[i + (long)n] + graw[i + 2L * n] + graw[i + 3L * n];
  const float m_ = eta * mom[i] - theta * gscale * g4;
  const float w_ = (1.0f - alpha) * w[i] + m_;
  outm[i] = m_;
  outw[i] = w_;
}

extern "C" void kernel_launch(void* const* d_in, const int* in_sizes, int n_in,
                              void* d_out, int out_size, void* d_ws, size_t ws_size,
                              hipStream_t stream) {
  (void)in_sizes; (void)n_in; (void)out_size; (void)ws_size;
  const float* X   = (const float*)d_in[0];
  const float* KP1 = (const float*)d_in[1];
  const float* KP2 = (const float*)d_in[2];
  const float* VP1 = (const float*)d_in[3];
  const float* VP2 = (const float*)d_in[4];
  const float* QP1 = (const float*)d_in[5];
  const float* QP2 = (const float*)d_in[6];
  const float* GDW = (const float*)d_in[7];
  const float* GDB = (const float*)d_in[8];
  const float* GLW = (const float*)d_in[9];
  const float* GLB = (const float*)d_in[10];
  const float* GMW = (const float*)d_in[11];
  const float* GMB = (const float*)d_in[12];
  const float* W0  = (const float*)d_in[13];  // (H,D) = (2048,1024)
  const float* W1  = (const float*)d_in[14];  // (D,H) = (1024,2048)
  const float* M0  = (const float*)d_in[15];
  const float* M1  = (const float*)d_in[16];
  const float* OW  = (const float*)d_in[17];

  char* ws = (char*)d_ws;
  const size_t MB = (size_t)1 << 20;
  u16* X16  = (u16*)(ws + 0 * MB);     // 16MB bf16 x
  u16* T1   = (u16*)(ws + 16 * MB);    // 16MB: t1 / retrieved / dpredraw
  u16* KEYS = (u16*)(ws + 32 * MB);    // 16MB
  u16* VALS = (u16*)(ws + 48 * MB);    // 16MB: values -> dpredT
  u16* QUER = (u16*)(ws + 64 * MB);    // 16MB: queries -> keysT
  u16* AQ   = (u16*)(ws + 80 * MB);    // 32MB: aq -> ak -> dhT
  u16* HK   = (u16*)(ws + 112 * MB);   // 32MB: hk -> dh (in-place DSILU)
  u16* AKT  = (u16*)(ws + 144 * MB);   // 32MB: akT
  u16* W1T  = (u16*)(ws + 176 * MB);   // 4MB
  u16* KP1b = (u16*)(ws + 180 * MB);
  u16* KP2b = (u16*)(ws + 182 * MB);
  u16* VP1b = (u16*)(ws + 184 * MB);
  u16* VP2b = (u16*)(ws + 186 * MB);
  u16* QP1b = (u16*)(ws + 188 * MB);
  u16* QP2b = (u16*)(ws + 190 * MB);
  u16* OWb  = (u16*)(ws + 192 * MB);
  u16* W0b  = (u16*)(ws + 194 * MB);   // 4MB
  u16* W1b  = (u16*)(ws + 198 * MB);   // 4MB
  float* G1R = (float*)(ws + 112 * MB);   // 32MB, aliases HK (dead by then)
  float* G0R = (float*)(ws + 0 * MB);     // 32MB, aliases X16+T1 (dead by then)
  float* XSUM = (float*)(ws + 202 * MB);  // 16KB
  float* GACC = (float*)(ws + 202 * MB + 16384);  // 3 floats

  float* OUT0  = (float*)d_out;        // (8192,1024)
  float* OUTW0 = OUT0 + 8388608;       // (2048,1024)
  float* OUTW1 = OUTW0 + 2097152;      // (1024,2048)
  float* OUTM0 = OUTW1 + 2097152;
  float* OUTM1 = OUTM0 + 2097152;

  hipMemsetAsync(XSUM, 0, 16384 + 64, stream);

  const dim3 blk(256);
#define GGRID(M_, N_, SK_) dim3((unsigned)(((M_) >> 7) * ((N_) >> 7) * (SK_)))

  // convert f32 inputs feeding GEMMs to bf16
  cvt_kernel<<<4096, blk, 0, stream>>>(X, X16, 8388608);
  cvt_kernel<<<512, blk, 0, stream>>>(KP1, KP1b, 1048576);
  cvt_kernel<<<512, blk, 0, stream>>>(KP2, KP2b, 1048576);
  cvt_kernel<<<512, blk, 0, stream>>>(VP1, VP1b, 1048576);
  cvt_kernel<<<512, blk, 0, stream>>>(VP2, VP2b, 1048576);
  cvt_kernel<<<512, blk, 0, stream>>>(QP1, QP1b, 1048576);
  cvt_kernel<<<512, blk, 0, stream>>>(QP2, QP2b, 1048576);
  cvt_kernel<<<512, blk, 0, stream>>>(OW, OWb, 1048576);
  cvt_kernel<<<1024, blk, 0, stream>>>(W0, W0b, 2097152);
  cvt_kernel<<<1024, blk, 0, stream>>>(W1, W1b, 2097152);

  // projections: t = silu(x@w1^T); p = silu(t@w2^T)
  gemm_nt<EPI_SILU><<<GGRID(8192,1024,1), blk, 0, stream>>>(X16, KP1b, T1,   nullptr, nullptr, 8192, 1024, 1024, 1);
  gemm_nt<EPI_SILU><<<GGRID(8192,1024,1), blk, 0, stream>>>(T1,  KP2b, KEYS, nullptr, nullptr, 8192, 1024, 1024, 1);
  gemm_nt<EPI_SILU><<<GGRID(8192,1024,1), blk, 0, stream>>>(X16, VP1b, T1,   nullptr, nullptr, 8192, 1024, 1024, 1);
  gemm_nt<EPI_SILU><<<GGRID(8192,1024,1), blk, 0, stream>>>(T1,  VP2b, VALS, nullptr, nullptr, 8192, 1024, 1024, 1);
  gemm_nt<EPI_SILU><<<GGRID(8192,1024,1), blk, 0, stream>>>(X16, QP1b, T1,   nullptr, nullptr, 8192, 1024, 1024, 1);
  gemm_nt<EPI_SILU><<<GGRID(8192,1024,1), blk, 0, stream>>>(T1,  QP2b, QUER, nullptr, nullptr, 8192, 1024, 1024, 1);
  l2norm_kernel<<<2048, blk, 0, stream>>>(KEYS);
  l2norm_kernel<<<2048, blk, 0, stream>>>(QUER);

  // memory read: retrieved = silu(q@w0^T)@w1^T ; out = retrieved@ow^T (f32 out)
  gemm_nt<EPI_SILU><<<GGRID(8192,2048,1), blk, 0, stream>>>(QUER, W0b, AQ,   nullptr, nullptr, 8192, 2048, 1024, 1);
  gemm_nt<EPI_BF16><<<GGRID(8192,1024,1), blk, 0, stream>>>(AQ,   W1b, T1,   nullptr, nullptr, 8192, 1024, 2048, 1);
  gemm_nt<EPI_F32><<<GGRID(8192,1024,1), blk, 0, stream>>>(T1,   OWb, OUT0, nullptr, nullptr, 8192, 1024, 1024, 1);

  // loss fwd: hk = keys@w0^T (stored), ak = silu(hk); dpredraw = ak@w1^T - values
  gemm_nt<EPI_SILU_PRE><<<GGRID(8192,2048,1), blk, 0, stream>>>(KEYS, W0b, AQ, nullptr, HK, 8192, 2048, 1024, 1);
  gemm_nt<EPI_DIFF><<<GGRID(8192,1024,1), blk, 0, stream>>>(AQ, W1b, T1, VALS, nullptr, 8192, 1024, 2048, 1);

  // dh = (dpredraw @ w1) * silu'(hk)  — needs w1^T; written in-place over hk
  transpose_kernel<<<dim3(32,16), blk, 0, stream>>>(W1b, W1T, 1024, 2048);
  gemm_nt<EPI_DSILU><<<GGRID(8192,2048,1), blk, 0, stream>>>(T1, W1T, HK, HK, nullptr, 8192, 2048, 1024, 1);

  // transposes for gradient GEMMs (order matters for buffer aliasing)
  transpose_kernel<<<dim3(16,128), blk, 0, stream>>>(T1, VALS, 8192, 1024);   // dpredT (1024,8192); T1 dead
  transpose_kernel<<<dim3(32,128), blk, 0, stream>>>(AQ, AKT, 8192, 2048);    // akT (2048,8192); AQ dead
  transpose_kernel<<<dim3(32,128), blk, 0, stream>>>(HK, AQ, 8192, 2048);     // dhT (2048,8192); HK dead
  transpose_kernel<<<dim3(16,128), blk, 0, stream>>>(KEYS, QUER, 8192, 1024); // keysT (1024,8192); KEYS dead

  // g1 = dpred^T @ ak  (G1R aliases HK region — HK consumed above)
  gemm_nt<EPI_F32S><<<GGRID(1024,2048,4), blk, 0, stream>>>(VALS, AKT, G1R, nullptr, nullptr, 1024, 2048, 8192, 4);
  // g0 = dh^T @ keys   (G0R aliases X16+T1 region — both dead)
  gemm_nt<EPI_F32S><<<GGRID(2048,1024,4), blk, 0, stream>>>(AQ, QUER, G0R, nullptr, nullptr, 2048, 1024, 8192, 4);

  // gates
  xmean_kernel<<<dim3(16,16), blk, 0, stream>>>(X, XSUM);
  gates_kernel<<<3072, blk, 0, stream>>>(XSUM, GDW, GDB, GLW, GLB, GMW, GMB, GACC);

  // weight/momentum update; grad scale = 2/(N*D)
  const float gscale = 2.0f / 8388608.0f;
  update_kernel<<<8192, blk, 0, stream>>>(G0R, W0, M0, OUTW0, OUTM0, GACC, gscale, 2097152);
  update_kernel<<<8192, blk, 0, stream>>>(G1R, W1, M1, OUTW1, OUTM1, GACC, gscale, 2097152);
#undef GGRID
}

// Round 4
// 984.108 us; speedup vs baseline: 1.1842x; 1.1842x over previous
//
#include <hip/hip_runtime.h>
#include <hip/hip_bf16.h>
#include <stdint.h>

typedef unsigned short u16;
typedef u16 ushort8 __attribute__((ext_vector_type(8)));
typedef __bf16 bf16x8 __attribute__((ext_vector_type(8)));
typedef float f32x4 __attribute__((ext_vector_type(4)));

enum {
  EPI_F32S = 0,      // f32 out into split-K slice ks
  EPI_BF16 = 1,      // plain bf16 out
  EPI_SILU = 2,      // silu(v) -> bf16
  EPI_SILU_PRE = 3,  // X2 = v (preact), C = silu(v)
  EPI_DIFF = 4,      // C = v - X1
  EPI_DSILU = 5,     // C = v * silu'(X1)   (X1 may alias C)
  EPI_F32 = 6        // plain f32 out
};

__device__ __forceinline__ float bf2f(u16 u) {
  union { uint32_t i; float f; } c; c.i = ((uint32_t)u) << 16; return c.f;
}
__device__ __forceinline__ u16 f2bf(float f) {
  union { float f; uint32_t i; } c; c.f = f;
  uint32_t x = c.i;
  return (u16)((x + 0x7fffu + ((x >> 16) & 1u)) >> 16);  // RNE
}
__device__ __forceinline__ float sigm(float x) { return 1.0f / (1.0f + __expf(-x)); }

__device__ __forceinline__ void async_ld16(const u16* g, const u16* l) {
  __builtin_amdgcn_global_load_lds(
      (const __attribute__((address_space(1))) void*)(uintptr_t)g,
      (__attribute__((address_space(3))) void*)(uint32_t)(uintptr_t)l,
      16, 0, 0);
}

// f32 -> bf16 conversion, 8 elems/thread; n multiple of 8
__global__ __launch_bounds__(256)
void cvt_kernel(const float* __restrict__ in, u16* __restrict__ out, long n) {
  const long i = ((long)blockIdx.x * 256 + threadIdx.x) * 8;
  if (i >= n) return;
  f32x4 a = *(const f32x4*)(in + i);
  f32x4 b = *(const f32x4*)(in + i + 4);
  ushort8 v;
#pragma unroll
  for (int e = 0; e < 4; ++e) v[e] = f2bf(a[e]);
#pragma unroll
  for (int e = 0; e < 4; ++e) v[4 + e] = f2bf(b[e]);
  *(ushort8*)(out + i) = v;
}

// ---------------------------------------------------------------------------
// NT GEMM: C[M,N] = epi( sum_k A[m,k]*B[n,k] ), A:(M,K) B:(N,K) row-major bf16.
// 128x128 tile, BK=32, 256 threads (4 waves, 2x2), 16x16x32 bf16 MFMA.
// m97 structure: global_load_lds width-16 staging, single-buffer, 2 barriers.
// Split-K: grid = (M/128)*(N/128)*SK, slice ks covers k in [ks*K/SK, ...).
// ---------------------------------------------------------------------------
template<int EPI>
__global__ __launch_bounds__(256)
void gemm_nt(const u16* __restrict__ A, const u16* __restrict__ B,
             void* Cp, const u16* X1, u16* X2,
             int M, int N, int K, int SK) {
  __shared__ u16 lA[4096];  // [128][32]
  __shared__ u16 lB[4096];
  const int t = threadIdx.x;
  const int w = t >> 6, l = t & 63;
  const int nb = N >> 7;
  const int tilesPer = (M >> 7) * nb;
  int bid = blockIdx.x;
  const int ks = bid / tilesPer;
  bid -= ks * tilesPer;
  const int bm = bid / nb;
  const int bn = bid - bm * nb;
  const long mBase = (long)bm << 7;
  const long nBase = (long)bn << 7;
  const int wr = w >> 1, wc = w & 1;
  const int kLen = K / SK;

  f32x4 acc[4][4];
#pragma unroll
  for (int i = 0; i < 4; ++i)
#pragma unroll
    for (int j = 0; j < 4; ++j) acc[i][j] = f32x4{0.f, 0.f, 0.f, 0.f};

  // async staging: wave w, lane l loads 16B; row = w*16 + l/4, col = (l&3)*8
  // LDS dest is wave-uniform base + lane*16 (linear); lane->byte 16*l verified.
  const u16* gA = A + (mBase + (w << 4) + (l >> 2)) * (long)K + ((l & 3) << 3) + (long)ks * kLen;
  const u16* gB = B + (nBase + (w << 4) + (l >> 2)) * (long)K + ((l & 3) << 3) + (long)ks * kLen;
  const long rowStep = 64L * K;
  const u16* lAw = lA + (w << 9);  // wave-uniform LDS base (1KB per wave slab)
  const u16* lBw = lB + (w << 9);

  const int lr = l & 15;
  const int lk = (l >> 4) << 3;
  const int lg = l >> 4;

  for (int k0 = 0; k0 < kLen; k0 += 32) {
    __syncthreads();  // previous iteration's ds_reads done before overwrite
    async_ld16(gA + k0, lAw);
    async_ld16(gA + k0 + rowStep, lAw + 2048);
    async_ld16(gB + k0, lBw);
    async_ld16(gB + k0 + rowStep, lBw + 2048);
    __syncthreads();  // compiler emits s_waitcnt vmcnt(0) before barrier
    bf16x8 av[4], bv[4];
#pragma unroll
    for (int m = 0; m < 4; ++m) {
      ushort8 u = *(const ushort8*)&lA[((wr << 6) + (m << 4) + lr) * 32 + lk];
      av[m] = __builtin_bit_cast(bf16x8, u);
    }
#pragma unroll
    for (int n = 0; n < 4; ++n) {
      ushort8 u = *(const ushort8*)&lB[((wc << 6) + (n << 4) + lr) * 32 + lk];
      bv[n] = __builtin_bit_cast(bf16x8, u);
    }
#pragma unroll
    for (int m = 0; m < 4; ++m)
#pragma unroll
      for (int n = 0; n < 4; ++n)
        acc[m][n] = __builtin_amdgcn_mfma_f32_16x16x32_bf16(av[m], bv[n], acc[m][n], 0, 0, 0);
  }

  // epilogue: C/D frag layout col = lane&15, row = (lane>>4)*4 + r  (m89-verified)
#pragma unroll
  for (int m = 0; m < 4; ++m) {
#pragma unroll
    for (int n = 0; n < 4; ++n) {
#pragma unroll
      for (int r = 0; r < 4; ++r) {
        const long row = mBase + (wr << 6) + (m << 4) + (lg << 2) + r;
        const long col = nBase + (wc << 6) + (n << 4) + lr;
        const long idx = row * N + col;
        const float v = acc[m][n][r];
        if constexpr (EPI == EPI_F32S) {
          ((float*)Cp)[(long)ks * M * N + idx] = v;
        } else if constexpr (EPI == EPI_F32) {
          ((float*)Cp)[idx] = v;
        } else if constexpr (EPI == EPI_BF16) {
          ((u16*)Cp)[idx] = f2bf(v);
        } else if constexpr (EPI == EPI_SILU) {
          ((u16*)Cp)[idx] = f2bf(v * sigm(v));
        } else if constexpr (EPI == EPI_SILU_PRE) {
          X2[idx] = f2bf(v);
          ((u16*)Cp)[idx] = f2bf(v * sigm(v));
        } else if constexpr (EPI == EPI_DIFF) {
          ((u16*)Cp)[idx] = f2bf(v - bf2f(X1[idx]));
        } else if constexpr (EPI == EPI_DSILU) {
          const float h = bf2f(X1[idx]);
          const float s = sigm(h);
          ((u16*)Cp)[idx] = f2bf(v * (s + h * s * (1.0f - s)));
        }
      }
    }
  }
}

// row-wise L2 normalize, D=1024, bf16 in-place, one wave per row
__global__ __launch_bounds__(256)
void l2norm_kernel(u16* a) {
  const int w = threadIdx.x >> 6, l = threadIdx.x & 63;
  const long row = (long)blockIdx.x * 4 + w;
  u16* p = a + row * 1024 + l * 16;
  ushort8 v0 = *(const ushort8*)p;
  ushort8 v1 = *(const ushort8*)(p + 8);
  float ss = 0.0f;
#pragma unroll
  for (int e = 0; e < 8; ++e) { float f = bf2f(v0[e]); ss += f * f; }
#pragma unroll
  for (int e = 0; e < 8; ++e) { float f = bf2f(v1[e]); ss += f * f; }
#pragma unroll
  for (int off = 32; off >= 1; off >>= 1) ss += __shfl_xor(ss, off, 64);
  const float sc = 1.0f / fmaxf(sqrtf(ss), 1e-12f);
#pragma unroll
  for (int e = 0; e < 8; ++e) v0[e] = f2bf(bf2f(v0[e]) * sc);
#pragma unroll
  for (int e = 0; e < 8; ++e) v1[e] = f2bf(bf2f(v1[e]) * sc);
  *(ushort8*)p = v0;
  *(ushort8*)(p + 8) = v1;
}

// 64x64 LDS tile transpose, bf16, R,C multiples of 64. grid (C/64, R/64)
__global__ __launch_bounds__(256)
void transpose_kernel(const u16* __restrict__ in, u16* __restrict__ out, int R, int C) {
  __shared__ u16 tile[64 * 72];
  const int t = threadIdx.x;
  const long br = blockIdx.y, bc = blockIdx.x;
#pragma unroll
  for (int i = 0; i < 2; ++i) {
    const int e = i * 256 + t;
    const int r = e >> 3, c0 = (e & 7) << 3;
    ushort8 v = *(const ushort8*)&in[(br * 64 + r) * C + bc * 64 + c0];
    *(ushort8*)&tile[r * 72 + c0] = v;
  }
  __syncthreads();
#pragma unroll
  for (int i = 0; i < 2; ++i) {
    const int e = i * 256 + t;
    const int r = e >> 3, c0 = (e & 7) << 3;
    ushort8 v;
#pragma unroll
    for (int j = 0; j < 8; ++j) v[j] = tile[(c0 + j) * 72 + r];
    *(ushort8*)&out[(bc * 64 + r) * R + br * 64 + c0] = v;
  }
}

// x:(4,2048,1024) f32 -> xsum:(4,1024) f32 partial sums over S. grid (16,16)
__global__ __launch_bounds__(256)
void xmean_kernel(const float* __restrict__ x, float* __restrict__ xsum) {
  const int i = blockIdx.x * 256 + threadIdx.x;  // b*1024 + d
  const int b = i >> 10, d = i & 1023;
  const int s0 = blockIdx.y << 7;
  const float* p = x + ((long)b * 2048 + s0) * 1024 + d;
  float s = 0.0f;
  for (int k = 0; k < 128; ++k) s += p[(long)k * 1024];
  atomicAdd(&xsum[i], s);
}

// per-dot sigmoid -> gtmp[gw]; NO atomics (round-3 lesson: 12288 atomics on 3
// addresses serialized ~160us). One wave per dot, f32x4 loads.
__global__ __launch_bounds__(256)
void gates_kernel(const float* __restrict__ xsum,
                  const float* __restrict__ W0, const float* __restrict__ b0,
                  const float* __restrict__ W1, const float* __restrict__ b1,
                  const float* __restrict__ W2, const float* __restrict__ b2,
                  float* __restrict__ gtmp) {
  const int gw = blockIdx.x * 4 + (threadIdx.x >> 6);
  const int l = threadIdx.x & 63;
  const int g = gw >> 12;
  const int rem = gw & 4095;
  const int b = rem >> 10, j = rem & 1023;
  const float* W = (g == 0) ? W0 : ((g == 1) ? W1 : W2);
  const float* bias = (g == 0) ? b0 : ((g == 1) ? b1 : b2);
  const float* xr = xsum + (b << 10) + (l << 4);
  const float* wrow = W + ((long)j << 10) + (l << 4);
  float s = 0.0f;
#pragma unroll
  for (int q = 0; q < 4; ++q) {
    f32x4 wv = *(const f32x4*)(wrow + q * 4);
    f32x4 xv = *(const f32x4*)(xr + q * 4);
#pragma unroll
    for (int e = 0; e < 4; ++e) s += wv[e] * xv[e];
  }
#pragma unroll
  for (int off = 32; off >= 1; off >>= 1) s += __shfl_xor(s, off, 64);
  if (l == 0) {
    const float z = s * (1.0f / 2048.0f) + bias[j];
    gtmp[gw] = sigm(z);
  }
}

// reduce gtmp[3*4096] -> gacc[3]; grid 3 blocks x 256 threads, atomic-free
__global__ __launch_bounds__(256)
void gatesum_kernel(const float* __restrict__ gtmp, float* __restrict__ gacc) {
  __shared__ float red[4];
  const int g = blockIdx.x, t = threadIdx.x;
  const float* p = gtmp + g * 4096;
  float s = 0.0f;
#pragma unroll
  for (int k = 0; k < 16; ++k) s += p[t + k * 256];
#pragma unroll
  for (int off = 32; off >= 1; off >>= 1) s += __shfl_xor(s, off, 64);
  if ((t & 63) == 0) red[t >> 6] = s;
  __syncthreads();
  if (t == 0) gacc[g] = red[0] + red[1] + red[2] + red[3];
}

// new_m = eta*mom - theta*gscale*g ; new_w = (1-alpha)*w + new_m ; g summed over 4 split-K slices
__global__ __launch_bounds__(256)
void update_kernel(const float* __restrict__ graw, const float* __restrict__ w,
                   const float* __restrict__ mom, float* __restrict__ outw,
                   float* __restrict__ outm, const float* __restrict__ gacc,
                   float gscale, int n) {
  const int i = blockIdx.x * 256 + threadIdx.x;
  if (i >= n) return;
  const float alpha = gacc[0] * (1.0f / 4096.0f);
  const float theta = gacc[1] * (1.0f / 4096.0f);
  const float eta   = gacc[2] * (1.0f / 4096.0f);
  const float g4 = graw[i] + graw[i + (long)n] + graw[i + 2L * n] + graw[i + 3L * n];
  const float m_ = eta * mom[i] - theta * gscale * g4;
  const float w_ = (1.0f - alpha) * w[i] + m_;
  outm[i] = m_;
  outw[i] = w_;
}

extern "C" void kernel_launch(void* const* d_in, const int* in_sizes, int n_in,
                              void* d_out, int out_size, void* d_ws, size_t ws_size,
                              hipStream_t stream) {
  (void)in_sizes; (void)n_in; (void)out_size; (void)ws_size;
  const float* X   = (const float*)d_in[0];
  const float* KP1 = (const float*)d_in[1];
  const float* KP2 = (const float*)d_in[2];
  const float* VP1 = (const float*)d_in[3];
  const float* VP2 = (const float*)d_in[4];
  const float* QP1 = (const float*)d_in[5];
  const float* QP2 = (const float*)d_in[6];
  const float* GDW = (const float*)d_in[7];
  const float* GDB = (const float*)d_in[8];
  const float* GLW = (const float*)d_in[9];
  const float* GLB = (const float*)d_in[10];
  const float* GMW = (const float*)d_in[11];
  const float* GMB = (const float*)d_in[12];
  const float* W0  = (const float*)d_in[13];  // (H,D) = (2048,1024)
  const float* W1  = (const float*)d_in[14];  // (D,H) = (1024,2048)
  const float* M0  = (const float*)d_in[15];
  const float* M1  = (const float*)d_in[16];
  const float* OW  = (const float*)d_in[17];

  char* ws = (char*)d_ws;
  const size_t MB = (size_t)1 << 20;
  u16* X16  = (u16*)(ws + 0 * MB);     // 16MB bf16 x
  u16* T1   = (u16*)(ws + 16 * MB);    // 16MB: t1 / retrieved / dpredraw
  u16* KEYS = (u16*)(ws + 32 * MB);    // 16MB
  u16* VALS = (u16*)(ws + 48 * MB);    // 16MB: values -> dpredT
  u16* QUER = (u16*)(ws + 64 * MB);    // 16MB: queries -> keysT
  u16* AQ   = (u16*)(ws + 80 * MB);    // 32MB: aq -> ak -> dhT
  u16* HK   = (u16*)(ws + 112 * MB);   // 32MB: hk -> dh (in-place DSILU)
  u16* AKT  = (u16*)(ws + 144 * MB);   // 32MB: akT
  u16* W1T  = (u16*)(ws + 176 * MB);   // 4MB
  u16* KP1b = (u16*)(ws + 180 * MB);
  u16* KP2b = (u16*)(ws + 182 * MB);
  u16* VP1b = (u16*)(ws + 184 * MB);
  u16* VP2b = (u16*)(ws + 186 * MB);
  u16* QP1b = (u16*)(ws + 188 * MB);
  u16* QP2b = (u16*)(ws + 190 * MB);
  u16* OWb  = (u16*)(ws + 192 * MB);
  u16* W0b  = (u16*)(ws + 194 * MB);   // 4MB
  u16* W1b  = (u16*)(ws + 198 * MB);   // 4MB
  float* G1R = (float*)(ws + 112 * MB);   // 32MB, aliases HK (dead by then)
  float* G0R = (float*)(ws + 0 * MB);     // 32MB, aliases X16+T1 (dead by then)
  float* XSUM = (float*)(ws + 202 * MB);  // 16KB
  float* GACC = (float*)(ws + 202 * MB + 16384);   // 3 floats
  float* GTMP = (float*)(ws + 202 * MB + 20480);   // 48KB (12288 floats)

  float* OUT0  = (float*)d_out;        // (8192,1024)
  float* OUTW0 = OUT0 + 8388608;       // (2048,1024)
  float* OUTW1 = OUTW0 + 2097152;      // (1024,2048)
  float* OUTM0 = OUTW1 + 2097152;
  float* OUTM1 = OUTM0 + 2097152;

  hipMemsetAsync(XSUM, 0, 16384, stream);

  const dim3 blk(256);
#define GGRID(M_, N_, SK_) dim3((unsigned)(((M_) >> 7) * ((N_) >> 7) * (SK_)))

  // convert f32 inputs feeding GEMMs to bf16
  cvt_kernel<<<4096, blk, 0, stream>>>(X, X16, 8388608);
  cvt_kernel<<<512, blk, 0, stream>>>(KP1, KP1b, 1048576);
  cvt_kernel<<<512, blk, 0, stream>>>(KP2, KP2b, 1048576);
  cvt_kernel<<<512, blk, 0, stream>>>(VP1, VP1b, 1048576);
  cvt_kernel<<<512, blk, 0, stream>>>(VP2, VP2b, 1048576);
  cvt_kernel<<<512, blk, 0, stream>>>(QP1, QP1b, 1048576);
  cvt_kernel<<<512, blk, 0, stream>>>(QP2, QP2b, 1048576);
  cvt_kernel<<<512, blk, 0, stream>>>(OW, OWb, 1048576);
  cvt_kernel<<<1024, blk, 0, stream>>>(W0, W0b, 2097152);
  cvt_kernel<<<1024, blk, 0, stream>>>(W1, W1b, 2097152);

  // projections: t = silu(x@w1^T); p = silu(t@w2^T)
  gemm_nt<EPI_SILU><<<GGRID(8192,1024,1), blk, 0, stream>>>(X16, KP1b, T1,   nullptr, nullptr, 8192, 1024, 1024, 1);
  gemm_nt<EPI_SILU><<<GGRID(8192,1024,1), blk, 0, stream>>>(T1,  KP2b, KEYS, nullptr, nullptr, 8192, 1024, 1024, 1);
  gemm_nt<EPI_SILU><<<GGRID(8192,1024,1), blk, 0, stream>>>(X16, VP1b, T1,   nullptr, nullptr, 8192, 1024, 1024, 1);
  gemm_nt<EPI_SILU><<<GGRID(8192,1024,1), blk, 0, stream>>>(T1,  VP2b, VALS, nullptr, nullptr, 8192, 1024, 1024, 1);
  gemm_nt<EPI_SILU><<<GGRID(8192,1024,1), blk, 0, stream>>>(X16, QP1b, T1,   nullptr, nullptr, 8192, 1024, 1024, 1);
  gemm_nt<EPI_SILU><<<GGRID(8192,1024,1), blk, 0, stream>>>(T1,  QP2b, QUER, nullptr, nullptr, 8192, 1024, 1024, 1);
  l2norm_kernel<<<2048, blk, 0, stream>>>(KEYS);
  l2norm_kernel<<<2048, blk, 0, stream>>>(QUER);

  // memory read: retrieved = silu(q@w0^T)@w1^T ; out = retrieved@ow^T (f32 out)
  gemm_nt<EPI_SILU><<<GGRID(8192,2048,1), blk, 0, stream>>>(QUER, W0b, AQ,   nullptr, nullptr, 8192, 2048, 1024, 1);
  gemm_nt<EPI_BF16><<<GGRID(8192,1024,1), blk, 0, stream>>>(AQ,   W1b, T1,   nullptr, nullptr, 8192, 1024, 2048, 1);
  gemm_nt<EPI_F32><<<GGRID(8192,1024,1), blk, 0, stream>>>(T1,   OWb, OUT0, nullptr, nullptr, 8192, 1024, 1024, 1);

  // loss fwd: hk = keys@w0^T (stored), ak = silu(hk); dpredraw = ak@w1^T - values
  gemm_nt<EPI_SILU_PRE><<<GGRID(8192,2048,1), blk, 0, stream>>>(KEYS, W0b, AQ, nullptr, HK, 8192, 2048, 1024, 1);
  gemm_nt<EPI_DIFF><<<GGRID(8192,1024,1), blk, 0, stream>>>(AQ, W1b, T1, VALS, nullptr, 8192, 1024, 2048, 1);

  // dh = (dpredraw @ w1) * silu'(hk)  — needs w1^T; written in-place over hk
  transpose_kernel<<<dim3(32,16), blk, 0, stream>>>(W1b, W1T, 1024, 2048);
  gemm_nt<EPI_DSILU><<<GGRID(8192,2048,1), blk, 0, stream>>>(T1, W1T, HK, HK, nullptr, 8192, 2048, 1024, 1);

  // transposes for gradient GEMMs (order matters for buffer aliasing)
  transpose_kernel<<<dim3(16,128), blk, 0, stream>>>(T1, VALS, 8192, 1024);   // dpredT (1024,8192); T1 dead
  transpose_kernel<<<dim3(32,128), blk, 0, stream>>>(AQ, AKT, 8192, 2048);    // akT (2048,8192); AQ dead
  transpose_kernel<<<dim3(32,128), blk, 0, stream>>>(HK, AQ, 8192, 2048);     // dhT (2048,8192); HK dead
  transpose_kernel<<<dim3(16,128), blk, 0, stream>>>(KEYS, QUER, 8192, 1024); // keysT (1024,8192); KEYS dead

  // g1 = dpred^T @ ak  (G1R aliases HK region — HK consumed above)
  gemm_nt<EPI_F32S><<<GGRID(1024,2048,4), blk, 0, stream>>>(VALS, AKT, G1R, nullptr, nullptr, 1024, 2048, 8192, 4);
  // g0 = dh^T @ keys   (G0R aliases X16+T1 region — both dead)
  gemm_nt<EPI_F32S><<<GGRID(2048,1024,4), blk, 0, stream>>>(AQ, QUER, G0R, nullptr, nullptr, 2048, 1024, 8192, 4);

  // gates (atomic-free)
  xmean_kernel<<<dim3(16,16), blk, 0, stream>>>(X, XSUM);
  gates_kernel<<<3072, blk, 0, stream>>>(XSUM, GDW, GDB, GLW, GLB, GMW, GMB, GTMP);
  gatesum_kernel<<<3, blk, 0, stream>>>(GTMP, GACC);

  // weight/momentum update; grad scale = 2/(N*D)
  const float gscale = 2.0f / 8388608.0f;
  update_kernel<<<8192, blk, 0, stream>>>(G0R, W0, M0, OUTW0, OUTM0, GACC, gscale, 2097152);
  update_kernel<<<8192, blk, 0, stream>>>(G1R, W1, M1, OUTW1, OUTM1, GACC, gscale, 2097152);
#undef GGRID
}

// Round 5
// 893.989 us; speedup vs baseline: 1.3036x; 1.1008x over previous
//
#include <hip/hip_runtime.h>
#include <hip/hip_bf16.h>
#include <stdint.h>

typedef unsigned short u16;
typedef u16 ushort8 __attribute__((ext_vector_type(8)));
typedef __bf16 bf16x8 __attribute__((ext_vector_type(8)));
typedef float f32x4 __attribute__((ext_vector_type(4)));

enum {
  EPI_F32S = 0,      // f32 out into split-K slice ks
  EPI_BF16 = 1,      // plain bf16 out
  EPI_SILU = 2,      // silu(v) -> bf16
  EPI_SILU_PRE = 3,  // X2 = v (preact), C = silu(v)
  EPI_DIFF = 4,      // C = v - X1
  EPI_DSILU = 5,     // C = v * silu'(X1)   (X1 may alias C)
  EPI_F32 = 6        // plain f32 out
};

__device__ __forceinline__ float bf2f(u16 u) {
  union { uint32_t i; float f; } c; c.i = ((uint32_t)u) << 16; return c.f;
}
__device__ __forceinline__ u16 f2bf(float f) {
  union { float f; uint32_t i; } c; c.f = f;
  uint32_t x = c.i;
  return (u16)((x + 0x7fffu + ((x >> 16) & 1u)) >> 16);  // RNE
}
__device__ __forceinline__ float sigm(float x) { return 1.0f / (1.0f + __expf(-x)); }

__device__ __forceinline__ void async_ld16(const u16* g, const u16* l) {
  __builtin_amdgcn_global_load_lds(
      (const __attribute__((address_space(1))) void*)(uintptr_t)g,
      (__attribute__((address_space(3))) void*)(uint32_t)(uintptr_t)l,
      16, 0, 0);
}

// f32 -> bf16 conversion, 8 elems/thread; n multiple of 8
__global__ __launch_bounds__(256)
void cvt_kernel(const float* __restrict__ in, u16* __restrict__ out, long n) {
  const long i = ((long)blockIdx.x * 256 + threadIdx.x) * 8;
  if (i >= n) return;
  f32x4 a = *(const f32x4*)(in + i);
  f32x4 b = *(const f32x4*)(in + i + 4);
  ushort8 v;
#pragma unroll
  for (int e = 0; e < 4; ++e) v[e] = f2bf(a[e]);
#pragma unroll
  for (int e = 0; e < 4; ++e) v[4 + e] = f2bf(b[e]);
  *(ushort8*)(out + i) = v;
}

// ---------------------------------------------------------------------------
// NT GEMM, 256x256 tile, BK=64, 512 threads (8 waves 2Mx4N), double-buffered
// LDS (128KB), counted-vmcnt prefetch (T4), XOR-swizzled LDS (T2), setprio
// around MFMA clusters (T5), 4 phase barriers per K-tile.
// C[M,N] = epi(sum_k A[m,k]*B[n,k]); A:(M,K) lda, B:(N,K) ldb row-major bf16.
// LDS logical layout per buf: A [256][64], B [256][64], each split in two
// 128-row chunks of 16KB. Swizzle: phys_col_byte = col_byte ^ ((row&7)<<4).
// Staging uses global_load_lds with LINEAR dest + inverse-swizzled SOURCE:
// lane l covers rows r*64+w*8+(l>>3), source col 16B-slot = (l&7)^(l>>3).
// ---------------------------------------------------------------------------
template<int EPI>
__global__ __launch_bounds__(512, 2)
void gemm256(const u16* __restrict__ A, int lda,
             const u16* __restrict__ B, int ldb,
             void* __restrict__ Cp, const u16* __restrict__ X1, u16* __restrict__ X2,
             int M, int N, int K, int SK) {
  __shared__ u16 lds[65536];  // 128 KB
  const int t = threadIdx.x;
  const int w = t >> 6, l = t & 63;
  const int nb = N >> 8;
  const int tilesPer = (M >> 8) * nb;
  int bid = blockIdx.x;
  const int ks = bid / tilesPer; bid -= ks * tilesPer;
  const int bm = bid / nb, bn = bid - bm * nb;
  const long mBase = (long)bm << 8, nBase = (long)bn << 8;
  const int kLen = K / SK;
  const int NT = kLen >> 6;          // K-tiles of 64
  const int wr = w >> 2, wc = w & 3; // wave grid 2x4; wave tile 128x64
  const int lr = l & 15, lh = l >> 4;

  f32x4 acc[8][4];
#pragma unroll
  for (int i = 0; i < 8; ++i)
#pragma unroll
    for (int j = 0; j < 4; ++j) acc[i][j] = f32x4{0.f, 0.f, 0.f, 0.f};

  // ---- staging addressing (inverse-swizzled global source) ----
  const int colOff = (((l & 7) ^ (l >> 3)) << 3);       // elements
  const long rowLoc = (w << 3) + (l >> 3);              // 0..63
  const u16* gA = A + (mBase + rowLoc) * (long)lda + (long)ks * kLen + colOff;
  const u16* gB = B + (nBase + rowLoc) * (long)ldb + (long)ks * kLen + colOff;

  auto stage = [&](int buf, int kt) {
    const long kOff = (long)kt << 6;
    const u16* d = (const u16*)lds + buf * 32768 + (w << 9);  // wave-uniform
#pragma unroll
    for (int h = 0; h < 2; ++h)
#pragma unroll
      for (int r = 0; r < 2; ++r)
        async_ld16(gA + ((h << 7) + (r << 6)) * (long)lda + kOff,
                   d + (h << 13) + (r << 12));
#pragma unroll
    for (int h = 0; h < 2; ++h)
#pragma unroll
      for (int r = 0; r < 2; ++r)
        async_ld16(gB + ((h << 7) + (r << 6)) * (long)ldb + kOff,
                   d + 16384 + (h << 13) + (r << 12));
  };

  int cur = 0;
  stage(0, 0);  // prologue: tile 0 -> buf0 (8 outstanding per wave)

  // ---- read-side swizzled column (u16 units): (ksl*32 + lh*8) ^ ((lr&7)*8)
  const int swz = (lr & 7) << 3;
  const int scol0 = ((lh << 3) + 0) ^ swz;        // ksl=0
  const int scol1 = ((lh << 3) + 32) ^ swz;       // ksl=1
  const int rowB0 = (wc & 1) << 6;                // B row base within chunk

  for (int kt = 0; kt < NT; ++kt) {
    if (kt + 1 < NT) {
      stage(cur ^ 1, kt + 1);
      __builtin_amdgcn_sched_barrier(0);
      asm volatile("s_waitcnt vmcnt(8)" ::: "memory");  // tile kt landed (mine)
    } else {
      asm volatile("s_waitcnt vmcnt(0)" ::: "memory");
    }
    __builtin_amdgcn_s_barrier();                        // everyone's landed
    __builtin_amdgcn_sched_barrier(0);

    const u16* cA = (const u16*)lds + cur * 32768 + wr * 8192;
    const u16* cB = (const u16*)lds + cur * 32768 + 16384 + (wc >> 1) * 8192;

#pragma unroll
    for (int ksl = 0; ksl < 2; ++ksl) {
      const int sc = ksl ? scol1 : scol0;
      bf16x8 bfr[4];
#pragma unroll
      for (int n = 0; n < 4; ++n) {
        const int row = rowB0 + (n << 4) + lr;
        bfr[n] = __builtin_bit_cast(bf16x8, *(const ushort8*)(cB + row * 64 + sc));
      }
#pragma unroll
      for (int g = 0; g < 2; ++g) {
        bf16x8 afr[4];
#pragma unroll
        for (int mm = 0; mm < 4; ++mm) {
          const int row = (((g << 2) + mm) << 4) + lr;
          afr[mm] = __builtin_bit_cast(bf16x8, *(const ushort8*)(cA + row * 64 + sc));
        }
        __builtin_amdgcn_s_setprio(1);
#pragma unroll
        for (int mm = 0; mm < 4; ++mm)
#pragma unroll
          for (int n = 0; n < 4; ++n)
            acc[(g << 2) + mm][n] =
                __builtin_amdgcn_mfma_f32_16x16x32_bf16(afr[mm], bfr[n],
                                                        acc[(g << 2) + mm][n], 0, 0, 0);
        __builtin_amdgcn_s_setprio(0);
        __builtin_amdgcn_s_barrier();          // phase boundary (reads consumed)
        __builtin_amdgcn_sched_barrier(0);
      }
    }
    cur ^= 1;
  }

  // epilogue: frag C/D layout col = lane&15, row = (lane>>4)*4 + r (m89)
#pragma unroll
  for (int m = 0; m < 8; ++m) {
#pragma unroll
    for (int n = 0; n < 4; ++n) {
#pragma unroll
      for (int r = 0; r < 4; ++r) {
        const long row = mBase + (wr << 7) + (m << 4) + (lh << 2) + r;
        const long col = nBase + (wc << 6) + (n << 4) + lr;
        const long idx = row * N + col;
        const float v = acc[m][n][r];
        if constexpr (EPI == EPI_F32S) {
          ((float*)Cp)[(long)ks * M * N + idx] = v;
        } else if constexpr (EPI == EPI_F32) {
          ((float*)Cp)[idx] = v;
        } else if constexpr (EPI == EPI_BF16) {
          ((u16*)Cp)[idx] = f2bf(v);
        } else if constexpr (EPI == EPI_SILU) {
          ((u16*)Cp)[idx] = f2bf(v * sigm(v));
        } else if constexpr (EPI == EPI_SILU_PRE) {
          X2[idx] = f2bf(v);
          ((u16*)Cp)[idx] = f2bf(v * sigm(v));
        } else if constexpr (EPI == EPI_DIFF) {
          ((u16*)Cp)[idx] = f2bf(v - bf2f(X1[idx]));
        } else if constexpr (EPI == EPI_DSILU) {
          const float h = bf2f(X1[idx]);
          const float s = sigm(h);
          ((u16*)Cp)[idx] = f2bf(v * (s + h * s * (1.0f - s)));
        }
      }
    }
  }
}

// row-wise L2 normalize, D=1024, bf16 in-place, one wave per row
__global__ __launch_bounds__(256)
void l2norm_kernel(u16* a) {
  const int w = threadIdx.x >> 6, l = threadIdx.x & 63;
  const long row = (long)blockIdx.x * 4 + w;
  u16* p = a + row * 1024 + l * 16;
  ushort8 v0 = *(const ushort8*)p;
  ushort8 v1 = *(const ushort8*)(p + 8);
  float ss = 0.0f;
#pragma unroll
  for (int e = 0; e < 8; ++e) { float f = bf2f(v0[e]); ss += f * f; }
#pragma unroll
  for (int e = 0; e < 8; ++e) { float f = bf2f(v1[e]); ss += f * f; }
#pragma unroll
  for (int off = 32; off >= 1; off >>= 1) ss += __shfl_xor(ss, off, 64);
  const float sc = 1.0f / fmaxf(sqrtf(ss), 1e-12f);
#pragma unroll
  for (int e = 0; e < 8; ++e) v0[e] = f2bf(bf2f(v0[e]) * sc);
#pragma unroll
  for (int e = 0; e < 8; ++e) v1[e] = f2bf(bf2f(v1[e]) * sc);
  *(ushort8*)p = v0;
  *(ushort8*)(p + 8) = v1;
}

// 64x64 LDS tile transpose, bf16, R,C multiples of 64. grid (C/64, R/64)
__global__ __launch_bounds__(256)
void transpose_kernel(const u16* __restrict__ in, u16* __restrict__ out, int R, int C) {
  __shared__ u16 tile[64 * 72];
  const int t = threadIdx.x;
  const long br = blockIdx.y, bc = blockIdx.x;
#pragma unroll
  for (int i = 0; i < 2; ++i) {
    const int e = i * 256 + t;
    const int r = e >> 3, c0 = (e & 7) << 3;
    ushort8 v = *(const ushort8*)&in[(br * 64 + r) * C + bc * 64 + c0];
    *(ushort8*)&tile[r * 72 + c0] = v;
  }
  __syncthreads();
#pragma unroll
  for (int i = 0; i < 2; ++i) {
    const int e = i * 256 + t;
    const int r = e >> 3, c0 = (e & 7) << 3;
    ushort8 v;
#pragma unroll
    for (int j = 0; j < 8; ++j) v[j] = tile[(c0 + j) * 72 + r];
    *(ushort8*)&out[(bc * 64 + r) * R + br * 64 + c0] = v;
  }
}

// x:(4,2048,1024) f32 -> xsum:(4,1024) f32 partial sums over S. grid (16,16)
__global__ __launch_bounds__(256)
void xmean_kernel(const float* __restrict__ x, float* __restrict__ xsum) {
  const int i = blockIdx.x * 256 + threadIdx.x;  // b*1024 + d
  const int b = i >> 10, d = i & 1023;
  const int s0 = blockIdx.y << 7;
  const float* p = x + ((long)b * 2048 + s0) * 1024 + d;
  float s = 0.0f;
  for (int k = 0; k < 128; ++k) s += p[(long)k * 1024];
  atomicAdd(&xsum[i], s);
}

// per-dot sigmoid -> gtmp[gw]; atomic-free (round-3 lesson)
__global__ __launch_bounds__(256)
void gates_kernel(const float* __restrict__ xsum,
                  const float* __restrict__ W0, const float* __restrict__ b0,
                  const float* __restrict__ W1, const float* __restrict__ b1,
                  const float* __restrict__ W2, const float* __restrict__ b2,
                  float* __restrict__ gtmp) {
  const int gw = blockIdx.x * 4 + (threadIdx.x >> 6);
  const int l = threadIdx.x & 63;
  const int g = gw >> 12;
  const int rem = gw & 4095;
  const int b = rem >> 10, j = rem & 1023;
  const float* W = (g == 0) ? W0 : ((g == 1) ? W1 : W2);
  const float* bias = (g == 0) ? b0 : ((g == 1) ? b1 : b2);
  const float* xr = xsum + (b << 10) + (l << 4);
  const float* wrow = W + ((long)j << 10) + (l << 4);
  float s = 0.0f;
#pragma unroll
  for (int q = 0; q < 4; ++q) {
    f32x4 wv = *(const f32x4*)(wrow + q * 4);
    f32x4 xv = *(const f32x4*)(xr + q * 4);
#pragma unroll
    for (int e = 0; e < 4; ++e) s += wv[e] * xv[e];
  }
#pragma unroll
  for (int off = 32; off >= 1; off >>= 1) s += __shfl_xor(s, off, 64);
  if (l == 0) {
    const float z = s * (1.0f / 2048.0f) + bias[j];
    gtmp[gw] = sigm(z);
  }
}

// reduce gtmp[3*4096] -> gacc[3]; 3 blocks, atomic-free
__global__ __launch_bounds__(256)
void gatesum_kernel(const float* __restrict__ gtmp, float* __restrict__ gacc) {
  __shared__ float red[4];
  const int g = blockIdx.x, t = threadIdx.x;
  const float* p = gtmp + g * 4096;
  float s = 0.0f;
#pragma unroll
  for (int k = 0; k < 16; ++k) s += p[t + k * 256];
#pragma unroll
  for (int off = 32; off >= 1; off >>= 1) s += __shfl_xor(s, off, 64);
  if ((t & 63) == 0) red[t >> 6] = s;
  __syncthreads();
  if (t == 0) gacc[g] = red[0] + red[1] + red[2] + red[3];
}

// new_m = eta*mom - theta*gscale*g ; new_w = (1-alpha)*w + new_m ; 8 slices
__global__ __launch_bounds__(256)
void update_kernel(const float* __restrict__ graw, const float* __restrict__ w,
                   const float* __restrict__ mom, float* __restrict__ outw,
                   float* __restrict__ outm, const float* __restrict__ gacc,
                   float gscale, int n) {
  const int i = blockIdx.x * 256 + threadIdx.x;
  if (i >= n) return;
  const float alpha = gacc[0] * (1.0f / 4096.0f);
  const float theta = gacc[1] * (1.0f / 4096.0f);
  const float eta   = gacc[2] * (1.0f / 4096.0f);
  float g8 = 0.0f;
#pragma unroll
  for (int s = 0; s < 8; ++s) g8 += graw[i + (long)s * n];
  const float m_ = eta * mom[i] - theta * gscale * g8;
  const float w_ = (1.0f - alpha) * w[i] + m_;
  outm[i] = m_;
  outw[i] = w_;
}

extern "C" void kernel_launch(void* const* d_in, const int* in_sizes, int n_in,
                              void* d_out, int out_size, void* d_ws, size_t ws_size,
                              hipStream_t stream) {
  (void)in_sizes; (void)n_in; (void)out_size; (void)ws_size;
  const float* X   = (const float*)d_in[0];
  const float* KP1 = (const float*)d_in[1];
  const float* KP2 = (const float*)d_in[2];
  const float* VP1 = (const float*)d_in[3];
  const float* VP2 = (const float*)d_in[4];
  const float* QP1 = (const float*)d_in[5];
  const float* QP2 = (const float*)d_in[6];
  const float* GDW = (const float*)d_in[7];
  const float* GDB = (const float*)d_in[8];
  const float* GLW = (const float*)d_in[9];
  const float* GLB = (const float*)d_in[10];
  const float* GMW = (const float*)d_in[11];
  const float* GMB = (const float*)d_in[12];
  const float* W0  = (const float*)d_in[13];  // (2048,1024)
  const float* W1  = (const float*)d_in[14];  // (1024,2048)
  const float* M0  = (const float*)d_in[15];
  const float* M1  = (const float*)d_in[16];
  const float* OW  = (const float*)d_in[17];

  char* ws = (char*)d_ws;
  const size_t MB = (size_t)1 << 20;
  u16* X16  = (u16*)(ws + 0 * MB);     // 16MB
  u16* T1   = (u16*)(ws + 16 * MB);    // 16MB: t1 / retrieved / dpredraw
  u16* KEYS = (u16*)(ws + 32 * MB);    // 16MB
  u16* HK   = (u16*)(ws + 48 * MB);    // 32MB: hk -> dh (in-place)
  u16* VALS = (u16*)(ws + 80 * MB);    // 16MB: values -> dpredT
  u16* QUER = (u16*)(ws + 96 * MB);    // 16MB: queries -> keysT
  u16* AQ   = (u16*)(ws + 112 * MB);   // 32MB: aq/ak -> dhT
  u16* AKT  = (u16*)(ws + 144 * MB);   // 32MB: akT (after TKV dead)
  u16* TKV  = (u16*)(ws + 144 * MB);   // 48MB (144-192): layer-1 out; dead before AKT
  u16* W1T  = (u16*)(ws + 192 * MB);   // 4MB
  u16* WCAT = (u16*)(ws + 196 * MB);   // 6MB (kp1|vp1|qp1 rows)
  u16* KP2b = (u16*)(ws + 202 * MB);
  u16* VP2b = (u16*)(ws + 204 * MB);
  u16* QP2b = (u16*)(ws + 206 * MB);
  u16* OWb  = (u16*)(ws + 208 * MB);
  u16* W0b  = (u16*)(ws + 210 * MB);   // 4MB
  u16* W1b  = (u16*)(ws + 214 * MB);   // 4MB
  float* GR   = (float*)(ws + 16 * MB);       // 64MB (16-80): T1/KEYS/HK dead by grad time
  float* XSUM = (float*)(ws + 218 * MB);      // 16KB
  float* GACC = (float*)(ws + 218 * MB + 16384);
  float* GTMP = (float*)(ws + 218 * MB + 20480);  // 48KB

  float* OUT0  = (float*)d_out;        // (8192,1024)
  float* OUTW0 = OUT0 + 8388608;
  float* OUTW1 = OUTW0 + 2097152;
  float* OUTM0 = OUTW1 + 2097152;
  float* OUTM1 = OUTM0 + 2097152;

  hipMemsetAsync(XSUM, 0, 16384, stream);

  const dim3 blk(256), blk512(512);
#define G256(M_, N_, SK_) dim3((unsigned)(((M_) >> 8) * ((N_) >> 8) * (SK_)))

  // f32 -> bf16 conversions (WCAT = [kp1;vp1;qp1])
  cvt_kernel<<<4096, blk, 0, stream>>>(X, X16, 8388608);
  cvt_kernel<<<512, blk, 0, stream>>>(KP1, WCAT, 1048576);
  cvt_kernel<<<512, blk, 0, stream>>>(VP1, WCAT + 1048576, 1048576);
  cvt_kernel<<<512, blk, 0, stream>>>(QP1, WCAT + 2097152, 1048576);
  cvt_kernel<<<512, blk, 0, stream>>>(KP2, KP2b, 1048576);
  cvt_kernel<<<512, blk, 0, stream>>>(VP2, VP2b, 1048576);
  cvt_kernel<<<512, blk, 0, stream>>>(QP2, QP2b, 1048576);
  cvt_kernel<<<512, blk, 0, stream>>>(OW, OWb, 1048576);
  cvt_kernel<<<1024, blk, 0, stream>>>(W0, W0b, 2097152);
  cvt_kernel<<<1024, blk, 0, stream>>>(W1, W1b, 2097152);
  transpose_kernel<<<dim3(32, 16), blk, 0, stream>>>(W1b, W1T, 1024, 2048);

  // gates (independent of everything else; GACC needed before updates)
  xmean_kernel<<<dim3(16, 16), blk, 0, stream>>>(X, XSUM);
  gates_kernel<<<3072, blk, 0, stream>>>(XSUM, GDW, GDB, GLW, GLB, GMW, GMB, GTMP);
  gatesum_kernel<<<3, blk, 0, stream>>>(GTMP, GACC);

  // layer-1 (batched K/V/Q): TKV = silu(x @ WCAT^T)  (8192 x 3072)
  gemm256<EPI_SILU><<<G256(8192, 3072, 1), blk512, 0, stream>>>(X16, 1024, WCAT, 1024, TKV, nullptr, nullptr, 8192, 3072, 1024, 1);
  // layer-2: keys/values/queries = silu(t_* @ W2^T), t_* = TKV columns
  gemm256<EPI_SILU><<<G256(8192, 1024, 1), blk512, 0, stream>>>(TKV + 0, 3072, KP2b, 1024, KEYS, nullptr, nullptr, 8192, 1024, 1024, 1);
  gemm256<EPI_SILU><<<G256(8192, 1024, 1), blk512, 0, stream>>>(TKV + 1024, 3072, VP2b, 1024, VALS, nullptr, nullptr, 8192, 1024, 1024, 1);
  gemm256<EPI_SILU><<<G256(8192, 1024, 1), blk512, 0, stream>>>(TKV + 2048, 3072, QP2b, 1024, QUER, nullptr, nullptr, 8192, 1024, 1024, 1);
  l2norm_kernel<<<2048, blk, 0, stream>>>(KEYS);
  l2norm_kernel<<<2048, blk, 0, stream>>>(QUER);

  // memory read path: retrieved = silu(q@w0^T)@w1^T ; out = retrieved@ow^T
  gemm256<EPI_SILU><<<G256(8192, 2048, 1), blk512, 0, stream>>>(QUER, 1024, W0b, 1024, AQ, nullptr, nullptr, 8192, 2048, 1024, 1);
  gemm256<EPI_BF16><<<G256(8192, 1024, 1), blk512, 0, stream>>>(AQ, 2048, W1b, 2048, T1, nullptr, nullptr, 8192, 1024, 2048, 1);
  gemm256<EPI_F32><<<G256(8192, 1024, 1), blk512, 0, stream>>>(T1, 1024, OWb, 1024, OUT0, nullptr, nullptr, 8192, 1024, 1024, 1);

  // loss fwd: hk = keys@w0^T (stored), ak = silu(hk); dpredraw = ak@w1^T - values
  gemm256<EPI_SILU_PRE><<<G256(8192, 2048, 1), blk512, 0, stream>>>(KEYS, 1024, W0b, 1024, AQ, nullptr, HK, 8192, 2048, 1024, 1);
  gemm256<EPI_DIFF><<<G256(8192, 1024, 1), blk512, 0, stream>>>(AQ, 2048, W1b, 2048, T1, VALS, nullptr, 8192, 1024, 2048, 1);
  // dh = (dpredraw @ w1) * silu'(hk) — in-place over HK
  gemm256<EPI_DSILU><<<G256(8192, 2048, 1), blk512, 0, stream>>>(T1, 1024, W1T, 1024, HK, HK, nullptr, 8192, 2048, 1024, 1);

  // transposes for gradient GEMMs
  transpose_kernel<<<dim3(16, 128), blk, 0, stream>>>(T1, VALS, 8192, 1024);   // dpredT; T1 dead
  transpose_kernel<<<dim3(32, 128), blk, 0, stream>>>(AQ, AKT, 8192, 2048);    // akT; AQ dead (TKV long dead)
  transpose_kernel<<<dim3(32, 128), blk, 0, stream>>>(HK, AQ, 8192, 2048);     // dhT; HK dead
  transpose_kernel<<<dim3(16, 128), blk, 0, stream>>>(KEYS, QUER, 8192, 1024); // keysT; KEYS dead

  const float gscale = 2.0f / 8388608.0f;
  // g1 = dpredT @ akT^T (1024x2048, K=8192, SK=8) -> GR slices; update W1
  gemm256<EPI_F32S><<<G256(1024, 2048, 8), blk512, 0, stream>>>(VALS, 8192, AKT, 8192, GR, nullptr, nullptr, 1024, 2048, 8192, 8);
  update_kernel<<<8192, blk, 0, stream>>>(GR, W1, M1, OUTW1, OUTM1, GACC, gscale, 2097152);
  // g0 = dhT @ keysT^T (2048x1024, K=8192, SK=8) -> GR slices; update W0
  gemm256<EPI_F32S><<<G256(2048, 1024, 8), blk512, 0, stream>>>(AQ, 8192, QUER, 8192, GR, nullptr, nullptr, 2048, 1024, 8192, 8);
  update_kernel<<<8192, blk, 0, stream>>>(GR, W0, M0, OUTW0, OUTM0, GACC, gscale, 2097152);
#undef G256
}